// Round 3
// baseline (9995.663 us; speedup 1.0000x reference)
//
#include <hip/hip_runtime.h>
#include <hip/hip_bf16.h>

#define BB 2
#define SS 2048
#define DD 1024
#define HH 16
#define DH 64
#define N3 3072

typedef __hip_bfloat16 bf16;

__device__ __forceinline__ float b2f(bf16 x) { return __bfloat162float(x); }

// ---------------- Kernel 1: QKV GEMM ----------------
// C[M=4096, N=3072] = hidden[4096,1024] @ W[1024,3072] + bias (all fp32 in),
// scattered to Qh/Kh/Vh [B,H,S,DH] bf16 (fp32 accum inside).
__global__ __launch_bounds__(256) void qkv_gemm(const float* __restrict__ A,
                                                const float* __restrict__ W,
                                                const float* __restrict__ bias,
                                                bf16* __restrict__ Qh,
                                                bf16* __restrict__ Kh,
                                                bf16* __restrict__ Vh) {
    __shared__ float As[64][17];
    __shared__ float Bs[16][65];
    const int tid = threadIdx.x;
    const int tx = tid & 15, ty = tid >> 4;
    const int m0 = blockIdx.y * 64;
    const int n0 = blockIdx.x * 64;
    float acc[4][4] = {};
    for (int k0 = 0; k0 < DD; k0 += 16) {
        #pragma unroll
        for (int i = 0; i < 4; ++i) {
            int idx = tid + i * 256;
            int r = idx >> 4, c = idx & 15;
            As[r][c] = A[(size_t)(m0 + r) * DD + k0 + c];
        }
        #pragma unroll
        for (int i = 0; i < 4; ++i) {
            int idx = tid + i * 256;
            int r = idx >> 6, c = idx & 63;
            Bs[r][c] = W[(size_t)(k0 + r) * N3 + n0 + c];
        }
        __syncthreads();
        #pragma unroll
        for (int kk = 0; kk < 16; ++kk) {
            float a[4], b[4];
            #pragma unroll
            for (int i = 0; i < 4; ++i) a[i] = As[ty + 16 * i][kk];
            #pragma unroll
            for (int j = 0; j < 4; ++j) b[j] = Bs[kk][tx + 16 * j];
            #pragma unroll
            for (int i = 0; i < 4; ++i)
                #pragma unroll
                for (int j = 0; j < 4; ++j) acc[i][j] += a[i] * b[j];
        }
        __syncthreads();
    }
    #pragma unroll
    for (int i = 0; i < 4; ++i) {
        #pragma unroll
        for (int j = 0; j < 4; ++j) {
            int m = m0 + ty + 16 * i;
            int n = n0 + tx + 16 * j;
            float v = acc[i][j] + bias[n];
            int which = n >> 10;     // 0=q 1=k 2=v
            int d = n & 1023;
            int h = d >> 6, dh = d & 63;
            int b_ = m >> 11, s = m & 2047;
            bf16* dst = (which == 0) ? Qh : ((which == 1) ? Kh : Vh);
            dst[(((size_t)(b_ * HH + h)) * SS + s) * DH + dh] = __float2bfloat16(v);
        }
    }
}

// ---------------- Kernel 2: attention ----------------
// One block per (bh, 4 q-rows). Scores in LDS fp32, exact softmax, writes
// normalized P (fp32) to Wout and P@V (bf16) to Hh.
__global__ __launch_bounds__(256) void attn_kernel(const bf16* __restrict__ Qh,
                                                   const bf16* __restrict__ Kh,
                                                   const bf16* __restrict__ Vh,
                                                   float* __restrict__ Wout,
                                                   bf16* __restrict__ Hh) {
    const int tid = threadIdx.x;
    const int bh = blockIdx.y;         // 0..31
    const int q0 = blockIdx.x * 4;
    __shared__ float q_lds[4][64];
    __shared__ float sc[4][SS];
    __shared__ float red[4];
    __shared__ float pv[4][64];

    {
        int r = tid >> 6, d = tid & 63;
        q_lds[r][d] = b2f(Qh[((size_t)bh * SS + (q0 + r)) * DH + d]) * 0.125f;
    }
    __syncthreads();

    const int kmax = q0 + 3;
    for (int k = tid; k <= kmax; k += 256) {
        const __hip_bfloat162* kr2 =
            (const __hip_bfloat162*)&Kh[((size_t)bh * SS + k) * DH];
        float d0 = 0.f, d1 = 0.f, d2 = 0.f, d3 = 0.f;
        #pragma unroll
        for (int j = 0; j < 32; ++j) {
            __hip_bfloat162 kv = kr2[j];
            float kx = b2f(kv.x), ky = b2f(kv.y);
            d0 += q_lds[0][2*j]*kx + q_lds[0][2*j+1]*ky;
            d1 += q_lds[1][2*j]*kx + q_lds[1][2*j+1]*ky;
            d2 += q_lds[2][2*j]*kx + q_lds[2][2*j+1]*ky;
            d3 += q_lds[3][2*j]*kx + q_lds[3][2*j+1]*ky;
        }
        sc[0][k] = d0; sc[1][k] = d1; sc[2][k] = d2; sc[3][k] = d3;
    }
    __syncthreads();

    const int lane = tid & 63, wave = tid >> 6;
    for (int r = 0; r < 4; ++r) {
        const int qr = q0 + r;
        // row max
        float lm = -1e30f;
        for (int k = tid; k <= qr; k += 256) lm = fmaxf(lm, sc[r][k]);
        #pragma unroll
        for (int off = 32; off; off >>= 1) lm = fmaxf(lm, __shfl_down(lm, off, 64));
        if (lane == 0) red[wave] = lm;
        __syncthreads();
        float mrow = fmaxf(fmaxf(red[0], red[1]), fmaxf(red[2], red[3]));
        // exp + row sum
        float ls = 0.f;
        for (int k = tid; k <= qr; k += 256) {
            float e = __expf(sc[r][k] - mrow);
            sc[r][k] = e;
            ls += e;
        }
        #pragma unroll
        for (int off = 32; off; off >>= 1) ls += __shfl_down(ls, off, 64);
        __syncthreads();               // everyone done reading red (mrow)
        if (lane == 0) red[wave] = ls;
        __syncthreads();
        float inv = 1.f / (red[0] + red[1] + red[2] + red[3]);
        // write normalized row (zeros beyond causal bound)
        float* wrow = &Wout[((size_t)bh * SS + qr) * SS];
        for (int k = tid; k < SS; k += 256) {
            float p = (k <= qr) ? sc[r][k] * inv : 0.f;
            wrow[k] = p;
            if (k <= qr) sc[r][k] = p;
        }
        __syncthreads();
        // P @ V for this row
        int d = tid & 63, c = tid >> 6;   // c constant per wave -> sc broadcast
        float partial = 0.f;
        for (int k = c; k <= qr; k += 4)
            partial += sc[r][k] * b2f(Vh[((size_t)bh * SS + k) * DH + d]);
        pv[c][d] = partial;
        __syncthreads();
        if (c == 0)
            Hh[((size_t)bh * SS + qr) * DH + d] =
                __float2bfloat16(pv[0][d] + pv[1][d] + pv[2][d] + pv[3][d]);
        __syncthreads();
    }
}

// ---------------- Kernel 3: output projection ----------------
// out[4096,1024] = Hh(regathered)[4096,1024] @ Wp[1024,1024] + bias (fp32 out)
__global__ __launch_bounds__(256) void proj_gemm(const bf16* __restrict__ Hh,
                                                 const float* __restrict__ Wp,
                                                 const float* __restrict__ bias,
                                                 float* __restrict__ out) {
    __shared__ float As[64][17];
    __shared__ float Bs[16][65];
    const int tid = threadIdx.x;
    const int tx = tid & 15, ty = tid >> 4;
    const int m0 = blockIdx.y * 64;
    const int n0 = blockIdx.x * 64;
    float acc[4][4] = {};
    for (int k0 = 0; k0 < DD; k0 += 16) {
        #pragma unroll
        for (int i = 0; i < 4; ++i) {
            int idx = tid + i * 256;
            int r = idx >> 4, c = idx & 15;
            int m = m0 + r, k = k0 + c;
            // A[m][k] = Hh[b][h][s][dh], h=k>>6, dh=k&63
            As[r][c] = b2f(Hh[(((size_t)(m >> 11) * HH + (k >> 6)) * SS + (m & 2047)) * DH + (k & 63)]);
        }
        #pragma unroll
        for (int i = 0; i < 4; ++i) {
            int idx = tid + i * 256;
            int r = idx >> 6, c = idx & 63;
            Bs[r][c] = Wp[(size_t)(k0 + r) * DD + n0 + c];
        }
        __syncthreads();
        #pragma unroll
        for (int kk = 0; kk < 16; ++kk) {
            float a[4], b[4];
            #pragma unroll
            for (int i = 0; i < 4; ++i) a[i] = As[ty + 16 * i][kk];
            #pragma unroll
            for (int j = 0; j < 4; ++j) b[j] = Bs[kk][tx + 16 * j];
            #pragma unroll
            for (int i = 0; i < 4; ++i)
                #pragma unroll
                for (int j = 0; j < 4; ++j) acc[i][j] += a[i] * b[j];
        }
        __syncthreads();
    }
    #pragma unroll
    for (int i = 0; i < 4; ++i) {
        #pragma unroll
        for (int j = 0; j < 4; ++j) {
            int m = m0 + ty + 16 * i;
            int n = n0 + tx + 16 * j;
            out[(size_t)m * DD + n] = acc[i][j] + bias[n];
        }
    }
}

extern "C" void kernel_launch(void* const* d_in, const int* in_sizes, int n_in,
                              void* d_out, int out_size, void* d_ws, size_t ws_size,
                              hipStream_t stream) {
    const float* hidden   = (const float*)d_in[0];
    const float* c_attn_w = (const float*)d_in[1];
    const float* c_attn_b = (const float*)d_in[2];
    const float* c_proj_w = (const float*)d_in[3];
    const float* c_proj_b = (const float*)d_in[4];

    float* out_attn = (float*)d_out;                        // [B,S,D]
    float* out_w    = (float*)d_out + (size_t)BB * SS * DD; // [B,H,S,S]

    // bf16 scratch: 4 tensors x [B,H,S,DH] = 4 x 8 MB = 32 MB total
    bf16* Qh = (bf16*)d_ws;
    bf16* Kh = Qh + (size_t)BB * HH * SS * DH;
    bf16* Vh = Kh + (size_t)BB * HH * SS * DH;
    bf16* Hh = Vh + (size_t)BB * HH * SS * DH;

    qkv_gemm<<<dim3(N3 / 64, (BB * SS) / 64), 256, 0, stream>>>(
        hidden, c_attn_w, c_attn_b, Qh, Kh, Vh);
    attn_kernel<<<dim3(SS / 4, BB * HH), 256, 0, stream>>>(
        Qh, Kh, Vh, out_w, Hh);
    proj_gemm<<<dim3(DD / 64, (BB * SS) / 64), 256, 0, stream>>>(
        Hh, c_proj_w, c_proj_b, out_attn);
}